// Round 1
// 769.459 us; speedup vs baseline: 1.0204x; 1.0204x over previous
//
#include <hip/hip_runtime.h>
#include <stdint.h>

#define L_LAYERS 16
#define QD 2048
#define BATCH 4096

typedef __attribute__((ext_vector_type(8))) __bf16 bf16x8;
typedef __attribute__((ext_vector_type(4))) float f32x4;
typedef __attribute__((address_space(3))) uint32_t lds32_t;
typedef const __attribute__((address_space(1))) uint32_t glob32_t;

// async global->LDS, 16B per lane. LDS dest is wave-uniform base + lane*16.
__device__ __forceinline__ void async_load16(const void* g, void* l) {
    __builtin_amdgcn_global_load_lds((glob32_t*)(uintptr_t)g, (lds32_t*)(uintptr_t)l,
                                     16, 0, 0);
}

// float -> bf16 bits, round-to-nearest-even.
__device__ __forceinline__ unsigned short f2bf(float f) {
    uint32_t u = __float_as_uint(f);
    u += 0x7FFFu + ((u >> 16) & 1u);
    return (unsigned short)(u >> 16);
}

// ---------------------------------------------------------------------------
// scales[l][k] = cos(a0/2)*cos(a1/2)*cos(a2/2)
__global__ void scales_kernel(const float* __restrict__ ang, float* __restrict__ sc, int n) {
    int i = blockIdx.x * 256 + threadIdx.x;
    if (i < n) {
        float a0 = ang[3 * i + 0], a1 = ang[3 * i + 1], a2 = ang[3 * i + 2];
        sc[i] = __cosf(a0 * 0.5f) * __cosf(a1 * 0.5f) * __cosf(a2 * 0.5f);
    }
}

// fp32 input state -> bf16
__global__ void convert_in_kernel(const float* __restrict__ in,
                                  unsigned short* __restrict__ out, int n4) {
    int i = blockIdx.x * 256 + threadIdx.x;
    if (i < n4) {
        float4 v = ((const float4*)in)[i];
        ushort4 o;
        o.x = f2bf(v.x); o.y = f2bf(v.y); o.z = f2bf(v.z); o.w = f2bf(v.w);
        ((ushort4*)out)[i] = o;
    }
}

// A-form: dst[m][k] = bf16( W[2z][m][k] * s[2z][m] )  (row scale, no transpose)
__global__ void convert_a_all(const float* __restrict__ W, const float* __restrict__ sc,
                              unsigned short* __restrict__ out) {
    const int z = blockIdx.z;
    const float* src = W + (size_t)(2 * z) * QD * QD;
    const float* srow = sc + (2 * z) * QD;
    unsigned short* dst = out + (size_t)z * QD * QD;
    int i = blockIdx.x * 256 + threadIdx.x;      // float4 index; 512 per row
    float s = srow[i >> 9];
    float4 v = ((const float4*)src)[i];
    ushort4 o;
    o.x = f2bf(v.x * s); o.y = f2bf(v.y * s); o.z = f2bf(v.z * s); o.w = f2bf(v.w * s);
    ((ushort4*)dst)[i] = o;
}

// 64x64 tile: dst[n][k] = bf16( src[k][n] * scale[k] )   (transpose + scale-fold)
__device__ __forceinline__ void conv_tile_body(const float* __restrict__ src,
                                               const float* __restrict__ srow,
                                               unsigned short* __restrict__ dst) {
    __shared__ __align__(16) unsigned short tile[64][72];
    const int t = threadIdx.x;
    const int k0 = blockIdx.y * 64, n0 = blockIdx.x * 64;
    const int r = t >> 4;
    const int c = (t & 15) * 4;
#pragma unroll
    for (int rr = 0; rr < 64; rr += 16) {
        int k = k0 + r + rr;
        float s = srow ? srow[k] : 1.0f;
        float4 v = *(const float4*)(src + (size_t)k * QD + n0 + c);
        tile[c + 0][r + rr] = f2bf(v.x * s);
        tile[c + 1][r + rr] = f2bf(v.y * s);
        tile[c + 2][r + rr] = f2bf(v.z * s);
        tile[c + 3][r + rr] = f2bf(v.w * s);
    }
    __syncthreads();
    const int wr = t >> 3;
    const int wc = (t & 7) * 8;
#pragma unroll
    for (int rr = 0; rr < 64; rr += 32) {
        *(float4*)(dst + (size_t)(n0 + wr + rr) * QD + k0 + wc) =
            *(const float4*)(&tile[wr + rr][wc]);
    }
}

__global__ void convert_b_all(const float* __restrict__ W, const float* __restrict__ Mb,
                              const float* __restrict__ sc, unsigned short* __restrict__ out) {
    const int z = blockIdx.z;
    const float* src = (z < 8) ? (W + (size_t)(2 * z + 1) * QD * QD) : Mb;
    const float* srow = (z < 8) ? (sc + (2 * z + 1) * QD) : nullptr;
    unsigned short* dst = out + (size_t)z * QD * QD;
    conv_tile_body(src, srow, dst);
}

// ---------------------------------------------------------------------------
struct GemmBatch {
    const unsigned short* a[8];
    const unsigned short* b[8];
    void* c[8];
};

// ======================= 128-wide kernel (small levels) =====================
template <int OUT_BF16, int TM>
__global__ __launch_bounds__(256, TM == 128 ? 2 : 4)
void gemm_kernel(GemmBatch args) {
    constexpr int NI = TM / 32;
    __shared__ __align__(16) unsigned short ldsA[TM * 64];
    __shared__ __align__(16) unsigned short ldsB[128 * 64];
    const unsigned short* __restrict__ A  = args.a[blockIdx.z];
    const unsigned short* __restrict__ Bt = args.b[blockIdx.z];
    void* __restrict__ Cout = args.c[blockIdx.z];

    const int t = threadIdx.x;
    const int n0 = blockIdx.x * 128;
    const int m0 = blockIdx.y * TM;
    const int lane = t & 63;
    const int wave = t >> 6;
    const int wm = (wave & 1) * (TM / 2);
    const int wn = (wave >> 1) * 64;
    const int fr = lane & 15;
    const int quad = lane >> 4;

    f32x4 acc[NI][4] = {};

    const int sr = t >> 2;
    const int scol = (t & 3) * 8;
    const unsigned short* ga = A + (size_t)(m0 + sr) * QD + scol;
    const unsigned short* gb = Bt + (size_t)(n0 + sr) * QD + scol;
    unsigned short* la = ldsA + t * 8;
    unsigned short* lb = ldsB + t * 8;

    for (int k0 = 0; k0 < QD; k0 += 64) {
        __syncthreads();
        if constexpr (TM == 128) {
            async_load16(ga, la);
            async_load16(ga + 64 * QD, la + 2048);
            async_load16(ga + 32, la + 4096);
            async_load16(ga + 32 + 64 * QD, la + 6144);
        } else {
            async_load16(ga, la);
            async_load16(ga + 32, la + 2048);
        }
        async_load16(gb, lb);
        async_load16(gb + 64 * QD, lb + 2048);
        async_load16(gb + 32, lb + 4096);
        async_load16(gb + 32 + 64 * QD, lb + 6144);
        ga += 64;
        gb += 64;
        __syncthreads();

#pragma unroll
        for (int kk = 0; kk < 2; kk++) {
            const unsigned short* pa = ldsA + kk * (TM * 32);
            const unsigned short* pb = ldsB + kk * 4096;
            bf16x8 af[NI], bfr[4];
#pragma unroll
            for (int i = 0; i < NI; i++)
                af[i] = *(const bf16x8*)(pa + (wm + i * 16 + fr) * 32 + quad * 8);
#pragma unroll
            for (int j = 0; j < 4; j++)
                bfr[j] = *(const bf16x8*)(pb + (wn + j * 16 + fr) * 32 + quad * 8);
#pragma unroll
            for (int i = 0; i < NI; i++)
#pragma unroll
                for (int j = 0; j < 4; j++)
                    acc[i][j] = __builtin_amdgcn_mfma_f32_16x16x32_bf16(af[i], bfr[j],
                                                                        acc[i][j], 0, 0, 0);
        }
    }

#pragma unroll
    for (int i = 0; i < NI; i++) {
        const int gr = m0 + wm + i * 16 + quad * 4;
#pragma unroll
        for (int j = 0; j < 4; j++) {
            const int gc = n0 + wn + j * 16 + fr;
#pragma unroll
            for (int r = 0; r < 4; r++) {
                float v = acc[i][j][r];
                if (OUT_BF16)
                    ((unsigned short*)Cout)[(size_t)(gr + r) * QD + gc] = f2bf(v);
                else
                    ((float*)Cout)[(size_t)(gr + r) * QD + gc] = v;
            }
        }
    }
}

// ================== 256x256 8-phase kernel (batched levels) =================
// BM=BN=256, BK=64, 512 threads = 8 waves (2m x 4n), per-wave 128x64 output.
// LDS 128 KiB: A/B each 2 dbuf x 2 halves x [128][64] bf16, st_16x32 swizzle
// (byte ^= ((byte>>9)&1)<<5) applied via pre-swizzled global_load_lds source
// (linear dest) + swizzled ds_read addresses. Staging schedule (race-free,
// each slot staged only after the barrier following its last read):
//   tile t phases: p1 A1(t+1)->nbuf, p2 B1(t+1)->nbuf, p3 B0(t+2)->buf,
//                  p4 A0(t+2)->buf; one counted vmcnt(4) per K-tile (p4).
// Tail tiles stage clamped-k dummy data into slots never read again.
__device__ __forceinline__ void stage_half(const unsigned short* __restrict__ G,
                                           int row0, int k0,
                                           unsigned char* dst, int t) {
    const int r = t >> 3;
    const int c = ((t & 7) * 8) ^ (((t >> 5) & 1) * 16);   // pre-swizzled source col
    const unsigned short* g = G + (size_t)(row0 + r) * QD + k0 + c;
    async_load16(g, dst + t * 16);
    async_load16(g + 64 * QD, dst + 8192 + t * 16);
}

template <int OUT_BF16>
__global__ __launch_bounds__(512, 2)
void gemm256_kernel(GemmBatch args) {
    __shared__ __align__(16) unsigned char lds[131072];
    const unsigned short* __restrict__ A  = args.a[blockIdx.z];
    const unsigned short* __restrict__ Bt = args.b[blockIdx.z];
    void* __restrict__ Cout = args.c[blockIdx.z];

    const int t = threadIdx.x;
    const int lane = t & 63;
    const int wid = t >> 6;
    const int wm = (wid >> 2) * 128;       // 0 or 128
    const int wn = (wid & 3) * 64;         // 0,64,128,192
    const int fr = lane & 15;
    const int quad = lane >> 4;
    const int m0 = blockIdx.y * 256;
    const int n0 = blockIdx.x * 256;

    unsigned char* ldsA8 = lds;            // 64 KiB
    unsigned char* ldsB8 = lds + 65536;    // 64 KiB
    // row_local bit2 == fr bit2 for every fragment read -> swizzle is a
    // per-thread constant XOR on the 32s byte bit.
    const int swz = ((fr >> 2) & 1) << 5;
    const unsigned char* sA = ldsA8 + (wm >> 7) * 16384 + fr * 128 + ((quad * 16) ^ swz);
    const unsigned char* sB = ldsB8 + ((wn >> 7) & 1) * 16384 + (wn & 64) * 128
                              + fr * 128 + ((quad * 16) ^ swz);

    f32x4 acc[8][4] = {};
    bf16x8 af[4][2], bfA[2][2], bfB[2][2];

    constexpr int NT = QD / 64;            // 32 K-tiles

    // prologue: all of tile 0 + A0(1), B0(1); leave 2 halves (4 loads) in flight
    stage_half(A,  m0,       0,  ldsA8,         t);   // A0(0)
    stage_half(A,  m0 + 128, 0,  ldsA8 + 16384, t);   // A1(0)
    stage_half(Bt, n0,       0,  ldsB8,         t);   // B0(0)
    stage_half(Bt, n0 + 128, 0,  ldsB8 + 16384, t);   // B1(0)
    stage_half(A,  m0,       64, ldsA8 + 32768, t);   // A0(1)
    stage_half(Bt, n0,       64, ldsB8 + 32768, t);   // B0(1)
    asm volatile("s_waitcnt vmcnt(4)" ::: "memory");
    __builtin_amdgcn_s_barrier();

    for (int kt = 0; kt < NT; ++kt) {
        const int buf  = (kt & 1) << 15;
        const int nbuf = (~kt & 1) << 15;
        const int k1 = ((kt + 1) & (NT - 1)) << 6;   // clamped: tail stages are dummies
        const int k2 = ((kt + 2) & (NT - 1)) << 6;

        // ---- phase 1: read A(mf0-3)+B(nf0-1); stage A1(t+1); MFMA Q(0,0)
#pragma unroll
        for (int mf = 0; mf < 4; mf++)
#pragma unroll
            for (int kk = 0; kk < 2; kk++)
                af[mf][kk] = *(const bf16x8*)(sA + buf + mf * 2048 + kk * 64);
#pragma unroll
        for (int nf = 0; nf < 2; nf++)
#pragma unroll
            for (int kk = 0; kk < 2; kk++)
                bfA[nf][kk] = *(const bf16x8*)(sB + buf + nf * 2048 + kk * 64);
        stage_half(A, m0 + 128, k1, ldsA8 + nbuf + 16384, t);
        __builtin_amdgcn_s_barrier();
        __builtin_amdgcn_s_setprio(1);
#pragma unroll
        for (int mf = 0; mf < 4; mf++)
#pragma unroll
            for (int nf = 0; nf < 2; nf++)
#pragma unroll
                for (int kk = 0; kk < 2; kk++)
                    acc[mf][nf] = __builtin_amdgcn_mfma_f32_16x16x32_bf16(
                        af[mf][kk], bfA[nf][kk], acc[mf][nf], 0, 0, 0);
        __builtin_amdgcn_s_setprio(0);
        __builtin_amdgcn_s_barrier();

        // ---- phase 2: read B(nf2-3); stage B1(t+1); MFMA Q(0,1)
#pragma unroll
        for (int nf = 0; nf < 2; nf++)
#pragma unroll
            for (int kk = 0; kk < 2; kk++)
                bfB[nf][kk] = *(const bf16x8*)(sB + buf + (nf + 2) * 2048 + kk * 64);
        stage_half(Bt, n0 + 128, k1, ldsB8 + nbuf + 16384, t);
        __builtin_amdgcn_s_barrier();
        __builtin_amdgcn_s_setprio(1);
#pragma unroll
        for (int mf = 0; mf < 4; mf++)
#pragma unroll
            for (int nf = 0; nf < 2; nf++)
#pragma unroll
                for (int kk = 0; kk < 2; kk++)
                    acc[mf][nf + 2] = __builtin_amdgcn_mfma_f32_16x16x32_bf16(
                        af[mf][kk], bfB[nf][kk], acc[mf][nf + 2], 0, 0, 0);
        __builtin_amdgcn_s_setprio(0);
        __builtin_amdgcn_s_barrier();

        // ---- phase 3: read A(mf4-7); stage B0(t+2); MFMA Q(1,1)
#pragma unroll
        for (int mf = 0; mf < 4; mf++)
#pragma unroll
            for (int kk = 0; kk < 2; kk++)
                af[mf][kk] = *(const bf16x8*)(sA + buf + (mf + 4) * 2048 + kk * 64);
        stage_half(Bt, n0, k2, ldsB8 + buf, t);
        __builtin_amdgcn_s_barrier();
        __builtin_amdgcn_s_setprio(1);
#pragma unroll
        for (int mf = 0; mf < 4; mf++)
#pragma unroll
            for (int nf = 0; nf < 2; nf++)
#pragma unroll
                for (int kk = 0; kk < 2; kk++)
                    acc[mf + 4][nf + 2] = __builtin_amdgcn_mfma_f32_16x16x32_bf16(
                        af[mf][kk], bfB[nf][kk], acc[mf + 4][nf + 2], 0, 0, 0);
        __builtin_amdgcn_s_setprio(0);
        __builtin_amdgcn_s_barrier();

        // ---- phase 4: no ds reads (reuse af + held bfA); stage A0(t+2);
        //      MFMA Q(1,0); counted vmcnt -> next tile fully staged
        stage_half(A, m0, k2, ldsA8 + buf, t);
        __builtin_amdgcn_s_barrier();
        __builtin_amdgcn_s_setprio(1);
#pragma unroll
        for (int mf = 0; mf < 4; mf++)
#pragma unroll
            for (int nf = 0; nf < 2; nf++)
#pragma unroll
                for (int kk = 0; kk < 2; kk++)
                    acc[mf + 4][nf] = __builtin_amdgcn_mfma_f32_16x16x32_bf16(
                        af[mf][kk], bfA[nf][kk], acc[mf + 4][nf], 0, 0, 0);
        __builtin_amdgcn_s_setprio(0);
        asm volatile("s_waitcnt vmcnt(4)" ::: "memory");
        __builtin_amdgcn_s_barrier();
    }

    asm volatile("s_waitcnt vmcnt(0)" ::: "memory");  // drain dummy tail stages

    // epilogue: C/D layout col=lane&15, row=quad*4+reg (m89/m91-verified)
#pragma unroll
    for (int mf = 0; mf < 8; mf++) {
        const int gr = m0 + wm + mf * 16 + quad * 4;
#pragma unroll
        for (int nf = 0; nf < 4; nf++) {
            const int gc = n0 + wn + nf * 16 + fr;
#pragma unroll
            for (int r = 0; r < 4; r++) {
                float v = acc[mf][nf][r];
                if (OUT_BF16)
                    ((unsigned short*)Cout)[(size_t)(gr + r) * QD + gc] = f2bf(v);
                else
                    ((float*)Cout)[(size_t)(gr + r) * QD + gc] = v;
            }
        }
    }
}

// ---------------------------------------------------------------------------
extern "C" void kernel_launch(void* const* d_in, const int* in_sizes, int n_in,
                              void* d_out, int out_size, void* d_ws, size_t ws_size,
                              hipStream_t stream) {
    const float* input_state = (const float*)d_in[0];  // [4096][2048]
    const float* angles      = (const float*)d_in[1];  // [16][2048][3]
    const float* W           = (const float*)d_in[2];  // [16][2048][2048]
    const float* Mb          = (const float*)d_in[3];  // [2048][2048]

    const size_t mat = (size_t)QD * QD;
    char* ws = (char*)d_ws;
    float* scales = (float*)ws;
    size_t off = 131072;
    unsigned short* xb = (unsigned short*)(ws + off); off += (size_t)BATCH * QD * 2;
    unsigned short* WA = (unsigned short*)(ws + off); off += 8 * mat * 2;
    unsigned short* WB = (unsigned short*)(ws + off); off += 9 * mat * 2;
    unsigned short* T1 = (unsigned short*)(ws + off); off += 8 * mat * 2;
    unsigned short* T2 = (unsigned short*)(ws + off); off += 4 * mat * 2;
    unsigned short* T3 = (unsigned short*)(ws + off); off += 2 * mat * 2;
    unsigned short* T4 = (unsigned short*)(ws + off); off += mat * 2;
    unsigned short* T5 = (unsigned short*)(ws + off); off += mat * 2;

    scales_kernel<<<(L_LAYERS * QD + 255) / 256, 256, 0, stream>>>(angles, scales,
                                                                   L_LAYERS * QD);
    convert_in_kernel<<<(BATCH * QD / 4) / 256, 256, 0, stream>>>(input_state, xb,
                                                                  BATCH * QD / 4);
    convert_a_all<<<dim3(mat / 4 / 256, 1, 8), 256, 0, stream>>>(W, scales, WA);
    convert_b_all<<<dim3(QD / 64, QD / 64, 9), 256, 0, stream>>>(W, Mb, scales, WB);

    // Level 1: pair i covers layers (2i, 2i+1); odd pairs produce P^T via swap.
    GemmBatch b1{};
    for (int i = 0; i < 8; i++) {
        const unsigned short* wa = WA + (size_t)i * mat;
        const unsigned short* wb = WB + (size_t)i * mat;
        if ((i & 1) == 0) { b1.a[i] = wa; b1.b[i] = wb; }
        else              { b1.a[i] = wb; b1.b[i] = wa; }
        b1.c[i] = T1 + (size_t)i * mat;
    }
    gemm256_kernel<1><<<dim3(QD / 256, QD / 256, 8), 512, 0, stream>>>(b1);

    // Level 2
    GemmBatch b2{};
    for (int i = 0; i < 4; i++) {
        b2.a[i] = T1 + (size_t)(2 * i + (i & 1)) * mat;
        b2.b[i] = T1 + (size_t)(2 * i + 1 - (i & 1)) * mat;
        b2.c[i] = T2 + (size_t)i * mat;
    }
    gemm256_kernel<1><<<dim3(QD / 256, QD / 256, 4), 512, 0, stream>>>(b2);

    // Level 3 (128-tile kernel keeps full-GPU block count)
    GemmBatch b3{};
    for (int i = 0; i < 2; i++) {
        b3.a[i] = T2 + (size_t)(2 * i + (i & 1)) * mat;
        b3.b[i] = T2 + (size_t)(2 * i + 1 - (i & 1)) * mat;
        b3.c[i] = T3 + (size_t)i * mat;
    }
    gemm_kernel<1, 128><<<dim3(QD / 128, QD / 128, 2), 256, 0, stream>>>(b3);

    // Level 4
    GemmBatch b4{};
    b4.a[0] = T3; b4.b[0] = T3 + mat; b4.c[0] = T4;
    gemm_kernel<1, 64><<<dim3(QD / 128, QD / 64, 1), 256, 0, stream>>>(b4);

    // Level 5: T^T = M^T * S^T
    GemmBatch b5{};
    b5.a[0] = WB + 8 * mat; b5.b[0] = T4; b5.c[0] = T5;
    gemm_kernel<1, 64><<<dim3(QD / 128, QD / 64, 1), 256, 0, stream>>>(b5);

    // Apply: out = x * T, fp32 out
    GemmBatch ba{};
    ba.a[0] = xb; ba.b[0] = T5; ba.c[0] = d_out;
    gemm_kernel<0, 128><<<dim3(QD / 128, BATCH / 128, 1), 256, 0, stream>>>(ba);
}

// Round 2
// 744.656 us; speedup vs baseline: 1.0544x; 1.0333x over previous
//
#include <hip/hip_runtime.h>
#include <stdint.h>

#define L_LAYERS 16
#define QD 2048
#define BATCH 4096

typedef __attribute__((ext_vector_type(8))) __bf16 bf16x8;
typedef __attribute__((ext_vector_type(4))) float f32x4;
typedef __attribute__((address_space(3))) uint32_t lds32_t;
typedef const __attribute__((address_space(1))) uint32_t glob32_t;

// async global->LDS, 16B per lane. LDS dest is wave-uniform base + lane*16.
__device__ __forceinline__ void async_load16(const void* g, void* l) {
    __builtin_amdgcn_global_load_lds((glob32_t*)(uintptr_t)g, (lds32_t*)(uintptr_t)l,
                                     16, 0, 0);
}

// float -> bf16 bits, round-to-nearest-even.
__device__ __forceinline__ unsigned short f2bf(float f) {
    uint32_t u = __float_as_uint(f);
    u += 0x7FFFu + ((u >> 16) & 1u);
    return (unsigned short)(u >> 16);
}

// ---------------------------------------------------------------------------
// scales[l][k] = cos(a0/2)*cos(a1/2)*cos(a2/2)
__global__ void scales_kernel(const float* __restrict__ ang, float* __restrict__ sc, int n) {
    int i = blockIdx.x * 256 + threadIdx.x;
    if (i < n) {
        float a0 = ang[3 * i + 0], a1 = ang[3 * i + 1], a2 = ang[3 * i + 2];
        sc[i] = __cosf(a0 * 0.5f) * __cosf(a1 * 0.5f) * __cosf(a2 * 0.5f);
    }
}

// fp32 input state -> bf16
__global__ void convert_in_kernel(const float* __restrict__ in,
                                  unsigned short* __restrict__ out, int n4) {
    int i = blockIdx.x * 256 + threadIdx.x;
    if (i < n4) {
        float4 v = ((const float4*)in)[i];
        ushort4 o;
        o.x = f2bf(v.x); o.y = f2bf(v.y); o.z = f2bf(v.z); o.w = f2bf(v.w);
        ((ushort4*)out)[i] = o;
    }
}

// A-form: dst[m][k] = bf16( W[2z][m][k] * s[2z][m] )  (row scale, no transpose)
__global__ void convert_a_all(const float* __restrict__ W, const float* __restrict__ sc,
                              unsigned short* __restrict__ out) {
    const int z = blockIdx.z;
    const float* src = W + (size_t)(2 * z) * QD * QD;
    const float* srow = sc + (2 * z) * QD;
    unsigned short* dst = out + (size_t)z * QD * QD;
    int i = blockIdx.x * 256 + threadIdx.x;      // float4 index; 512 per row
    float s = srow[i >> 9];
    float4 v = ((const float4*)src)[i];
    ushort4 o;
    o.x = f2bf(v.x * s); o.y = f2bf(v.y * s); o.z = f2bf(v.z * s); o.w = f2bf(v.w * s);
    ((ushort4*)dst)[i] = o;
}

// 64x64 tile: dst[n][k] = bf16( src[k][n] * scale[k] )   (transpose + scale-fold)
__device__ __forceinline__ void conv_tile_body(const float* __restrict__ src,
                                               const float* __restrict__ srow,
                                               unsigned short* __restrict__ dst) {
    __shared__ __align__(16) unsigned short tile[64][72];
    const int t = threadIdx.x;
    const int k0 = blockIdx.y * 64, n0 = blockIdx.x * 64;
    const int r = t >> 4;
    const int c = (t & 15) * 4;
#pragma unroll
    for (int rr = 0; rr < 64; rr += 16) {
        int k = k0 + r + rr;
        float s = srow ? srow[k] : 1.0f;
        float4 v = *(const float4*)(src + (size_t)k * QD + n0 + c);
        tile[c + 0][r + rr] = f2bf(v.x * s);
        tile[c + 1][r + rr] = f2bf(v.y * s);
        tile[c + 2][r + rr] = f2bf(v.z * s);
        tile[c + 3][r + rr] = f2bf(v.w * s);
    }
    __syncthreads();
    const int wr = t >> 3;
    const int wc = (t & 7) * 8;
#pragma unroll
    for (int rr = 0; rr < 64; rr += 32) {
        *(float4*)(dst + (size_t)(n0 + wr + rr) * QD + k0 + wc) =
            *(const float4*)(&tile[wr + rr][wc]);
    }
}

__global__ void convert_b_all(const float* __restrict__ W, const float* __restrict__ Mb,
                              const float* __restrict__ sc, unsigned short* __restrict__ out) {
    const int z = blockIdx.z;
    const float* src = (z < 8) ? (W + (size_t)(2 * z + 1) * QD * QD) : Mb;
    const float* srow = (z < 8) ? (sc + (2 * z + 1) * QD) : nullptr;
    unsigned short* dst = out + (size_t)z * QD * QD;
    conv_tile_body(src, srow, dst);
}

// ---------------------------------------------------------------------------
struct GemmBatch {
    const unsigned short* a[8];
    const unsigned short* b[8];
    void* c[8];
};

// ======================= 128-wide kernel (small levels) =====================
// Kept unswizzled: T2 is measured-null on 2-phase structures (regime gate).
template <int OUT_BF16, int TM>
__global__ __launch_bounds__(256, TM == 128 ? 2 : 4)
void gemm_kernel(GemmBatch args) {
    constexpr int NI = TM / 32;
    __shared__ __align__(16) unsigned short ldsA[TM * 64];
    __shared__ __align__(16) unsigned short ldsB[128 * 64];
    const unsigned short* __restrict__ A  = args.a[blockIdx.z];
    const unsigned short* __restrict__ Bt = args.b[blockIdx.z];
    void* __restrict__ Cout = args.c[blockIdx.z];

    const int t = threadIdx.x;
    const int n0 = blockIdx.x * 128;
    const int m0 = blockIdx.y * TM;
    const int lane = t & 63;
    const int wave = t >> 6;
    const int wm = (wave & 1) * (TM / 2);
    const int wn = (wave >> 1) * 64;
    const int fr = lane & 15;
    const int quad = lane >> 4;

    f32x4 acc[NI][4] = {};

    const int sr = t >> 2;
    const int scol = (t & 3) * 8;
    const unsigned short* ga = A + (size_t)(m0 + sr) * QD + scol;
    const unsigned short* gb = Bt + (size_t)(n0 + sr) * QD + scol;
    unsigned short* la = ldsA + t * 8;
    unsigned short* lb = ldsB + t * 8;

    for (int k0 = 0; k0 < QD; k0 += 64) {
        __syncthreads();
        if constexpr (TM == 128) {
            async_load16(ga, la);
            async_load16(ga + 64 * QD, la + 2048);
            async_load16(ga + 32, la + 4096);
            async_load16(ga + 32 + 64 * QD, la + 6144);
        } else {
            async_load16(ga, la);
            async_load16(ga + 32, la + 2048);
        }
        async_load16(gb, lb);
        async_load16(gb + 64 * QD, lb + 2048);
        async_load16(gb + 32, lb + 4096);
        async_load16(gb + 32 + 64 * QD, lb + 6144);
        ga += 64;
        gb += 64;
        __syncthreads();

#pragma unroll
        for (int kk = 0; kk < 2; kk++) {
            const unsigned short* pa = ldsA + kk * (TM * 32);
            const unsigned short* pb = ldsB + kk * 4096;
            bf16x8 af[NI], bfr[4];
#pragma unroll
            for (int i = 0; i < NI; i++)
                af[i] = *(const bf16x8*)(pa + (wm + i * 16 + fr) * 32 + quad * 8);
#pragma unroll
            for (int j = 0; j < 4; j++)
                bfr[j] = *(const bf16x8*)(pb + (wn + j * 16 + fr) * 32 + quad * 8);
#pragma unroll
            for (int i = 0; i < NI; i++)
#pragma unroll
                for (int j = 0; j < 4; j++)
                    acc[i][j] = __builtin_amdgcn_mfma_f32_16x16x32_bf16(af[i], bfr[j],
                                                                        acc[i][j], 0, 0, 0);
        }
    }

#pragma unroll
    for (int i = 0; i < NI; i++) {
        const int gr = m0 + wm + i * 16 + quad * 4;
#pragma unroll
        for (int j = 0; j < 4; j++) {
            const int gc = n0 + wn + j * 16 + fr;
#pragma unroll
            for (int r = 0; r < 4; r++) {
                float v = acc[i][j][r];
                if (OUT_BF16)
                    ((unsigned short*)Cout)[(size_t)(gr + r) * QD + gc] = f2bf(v);
                else
                    ((float*)Cout)[(size_t)(gr + r) * QD + gc] = v;
            }
        }
    }
}

// ================== 256x256 8-phase kernel (batched levels) =================
// BM=BN=256, BK=64, 512 threads = 8 waves (2m x 4n), per-wave 128x64 output.
// LDS 128 KiB: A/B each 2 dbuf x 2 halves x [128 rows][64 cols] bf16.
// Bank-conflict fix (Guideline 4, 3-bit XOR for 128B rows):
//   lds_byte(row, col_byte) holds global col_byte ^ ((row&7)<<4).
// Applied as inverse-swizzled global_load_lds SOURCE (linear dest, rule #21)
// + swizzled ds_read addresses. For fragment reads row&7 == fr&7, so the mask
// folds to per-thread constants: bits 4-5 into the base pointer, bit 6 as a
// kk-slice swap (kk_eff = kk ^ fr_bit2), selected at compile time.
// Staging schedule (race-free; each slot staged only after the barrier
// following its last read): tile t phases: p1 A1(t+1)->nbuf, p2 B1(t+1)->nbuf,
// p3 B0(t+2)->buf, p4 A0(t+2)->buf; one counted vmcnt(4) per K-tile (p4).
// Tail tiles stage clamped-k dummy data into slots never read again.
__device__ __forceinline__ void stage_half(const unsigned short* __restrict__ G,
                                           int row0, int k0,
                                           unsigned char* dst, int t) {
    const int r = t >> 3;
    const int c = 8 * ((t & 7) ^ (r & 7));   // inverse-swizzled source col (elements)
    const unsigned short* g = G + (size_t)(row0 + r) * QD + k0 + c;
    async_load16(g, dst + t * 16);
    async_load16(g + 64 * QD, dst + 8192 + t * 16);   // rows 64..127: (r+64)&7 == r&7
}

template <int OUT_BF16>
__global__ __launch_bounds__(512, 2)
void gemm256_kernel(GemmBatch args) {
    __shared__ __align__(16) unsigned char lds[131072];
    const unsigned short* __restrict__ A  = args.a[blockIdx.z];
    const unsigned short* __restrict__ Bt = args.b[blockIdx.z];
    void* __restrict__ Cout = args.c[blockIdx.z];

    const int t = threadIdx.x;
    const int lane = t & 63;
    const int wid = t >> 6;
    const int wm = (wid >> 2) * 128;       // 0 or 128
    const int wn = (wid & 3) * 64;         // 0,64,128,192
    const int fr = lane & 15;
    const int quad = lane >> 4;
    const int m0 = blockIdx.y * 256;
    const int n0 = blockIdx.x * 256;

    unsigned char* ldsA8 = lds;            // 64 KiB
    unsigned char* ldsB8 = lds + 65536;    // 64 KiB
    // 3-bit swizzle folded per-thread: bits 4-5 from fr bits 0-1, bit 6 swaps kk.
    const int swz45 = (fr & 3) << 4;
    const int frb2 = (fr >> 2) & 1;
    const int kof0 = frb2 << 6;            // byte offset of k-slice kk=0
    const int kof1 = (frb2 ^ 1) << 6;      // byte offset of k-slice kk=1
    const unsigned char* sA = ldsA8 + (wm >> 7) * 16384 + fr * 128 + ((quad * 16) ^ swz45);
    const unsigned char* sB = ldsB8 + ((wn >> 7) & 1) * 16384 + (wn & 64) * 128
                              + fr * 128 + ((quad * 16) ^ swz45);

    f32x4 acc[8][4] = {};
    bf16x8 af[4][2], bfA[2][2], bfB[2][2];

    constexpr int NT = QD / 64;            // 32 K-tiles

    // prologue: all of tile 0 + A0(1), B0(1); leave 2 halves (4 loads) in flight
    stage_half(A,  m0,       0,  ldsA8,         t);   // A0(0)
    stage_half(A,  m0 + 128, 0,  ldsA8 + 16384, t);   // A1(0)
    stage_half(Bt, n0,       0,  ldsB8,         t);   // B0(0)
    stage_half(Bt, n0 + 128, 0,  ldsB8 + 16384, t);   // B1(0)
    stage_half(A,  m0,       64, ldsA8 + 32768, t);   // A0(1)
    stage_half(Bt, n0,       64, ldsB8 + 32768, t);   // B0(1)
    asm volatile("s_waitcnt vmcnt(4)" ::: "memory");
    __builtin_amdgcn_s_barrier();

    for (int kt = 0; kt < NT; ++kt) {
        const int buf  = (kt & 1) << 15;
        const int nbuf = (~kt & 1) << 15;
        const int k1 = ((kt + 1) & (NT - 1)) << 6;   // clamped: tail stages are dummies
        const int k2 = ((kt + 2) & (NT - 1)) << 6;

        // ---- phase 1: read A(mf0-3)+B(nf0-1); stage A1(t+1); MFMA Q(0,0)
#pragma unroll
        for (int mf = 0; mf < 4; mf++)
#pragma unroll
            for (int kk = 0; kk < 2; kk++)
                af[mf][kk] = *(const bf16x8*)(sA + buf + mf * 2048 + (kk ? kof1 : kof0));
#pragma unroll
        for (int nf = 0; nf < 2; nf++)
#pragma unroll
            for (int kk = 0; kk < 2; kk++)
                bfA[nf][kk] = *(const bf16x8*)(sB + buf + nf * 2048 + (kk ? kof1 : kof0));
        stage_half(A, m0 + 128, k1, ldsA8 + nbuf + 16384, t);
        __builtin_amdgcn_s_barrier();
        __builtin_amdgcn_s_setprio(1);
#pragma unroll
        for (int mf = 0; mf < 4; mf++)
#pragma unroll
            for (int nf = 0; nf < 2; nf++)
#pragma unroll
                for (int kk = 0; kk < 2; kk++)
                    acc[mf][nf] = __builtin_amdgcn_mfma_f32_16x16x32_bf16(
                        af[mf][kk], bfA[nf][kk], acc[mf][nf], 0, 0, 0);
        __builtin_amdgcn_s_setprio(0);
        __builtin_amdgcn_s_barrier();

        // ---- phase 2: read B(nf2-3); stage B1(t+1); MFMA Q(0,1)
#pragma unroll
        for (int nf = 0; nf < 2; nf++)
#pragma unroll
            for (int kk = 0; kk < 2; kk++)
                bfB[nf][kk] = *(const bf16x8*)(sB + buf + (nf + 2) * 2048 + (kk ? kof1 : kof0));
        stage_half(Bt, n0 + 128, k1, ldsB8 + nbuf + 16384, t);
        __builtin_amdgcn_s_barrier();
        __builtin_amdgcn_s_setprio(1);
#pragma unroll
        for (int mf = 0; mf < 4; mf++)
#pragma unroll
            for (int nf = 0; nf < 2; nf++)
#pragma unroll
                for (int kk = 0; kk < 2; kk++)
                    acc[mf][nf + 2] = __builtin_amdgcn_mfma_f32_16x16x32_bf16(
                        af[mf][kk], bfB[nf][kk], acc[mf][nf + 2], 0, 0, 0);
        __builtin_amdgcn_s_setprio(0);
        __builtin_amdgcn_s_barrier();

        // ---- phase 3: read A(mf4-7); stage B0(t+2); MFMA Q(1,1)
#pragma unroll
        for (int mf = 0; mf < 4; mf++)
#pragma unroll
            for (int kk = 0; kk < 2; kk++)
                af[mf][kk] = *(const bf16x8*)(sA + buf + (mf + 4) * 2048 + (kk ? kof1 : kof0));
        stage_half(Bt, n0, k2, ldsB8 + buf, t);
        __builtin_amdgcn_s_barrier();
        __builtin_amdgcn_s_setprio(1);
#pragma unroll
        for (int mf = 0; mf < 4; mf++)
#pragma unroll
            for (int nf = 0; nf < 2; nf++)
#pragma unroll
                for (int kk = 0; kk < 2; kk++)
                    acc[mf + 4][nf + 2] = __builtin_amdgcn_mfma_f32_16x16x32_bf16(
                        af[mf][kk], bfB[nf][kk], acc[mf + 4][nf + 2], 0, 0, 0);
        __builtin_amdgcn_s_setprio(0);
        __builtin_amdgcn_s_barrier();

        // ---- phase 4: no ds reads (reuse af + held bfA); stage A0(t+2);
        //      MFMA Q(1,0); counted vmcnt -> next tile fully staged
        stage_half(A, m0, k2, ldsA8 + buf, t);
        __builtin_amdgcn_s_barrier();
        __builtin_amdgcn_s_setprio(1);
#pragma unroll
        for (int mf = 0; mf < 4; mf++)
#pragma unroll
            for (int nf = 0; nf < 2; nf++)
#pragma unroll
                for (int kk = 0; kk < 2; kk++)
                    acc[mf + 4][nf] = __builtin_amdgcn_mfma_f32_16x16x32_bf16(
                        af[mf][kk], bfA[nf][kk], acc[mf + 4][nf], 0, 0, 0);
        __builtin_amdgcn_s_setprio(0);
        asm volatile("s_waitcnt vmcnt(4)" ::: "memory");
        __builtin_amdgcn_s_barrier();
    }

    asm volatile("s_waitcnt vmcnt(0)" ::: "memory");  // drain dummy tail stages

    // epilogue: C/D layout col=lane&15, row=quad*4+reg (m89/m91-verified)
#pragma unroll
    for (int mf = 0; mf < 8; mf++) {
        const int gr = m0 + wm + mf * 16 + quad * 4;
#pragma unroll
        for (int nf = 0; nf < 4; nf++) {
            const int gc = n0 + wn + nf * 16 + fr;
#pragma unroll
            for (int r = 0; r < 4; r++) {
                float v = acc[mf][nf][r];
                if (OUT_BF16)
                    ((unsigned short*)Cout)[(size_t)(gr + r) * QD + gc] = f2bf(v);
                else
                    ((float*)Cout)[(size_t)(gr + r) * QD + gc] = v;
            }
        }
    }
}

// ---------------------------------------------------------------------------
extern "C" void kernel_launch(void* const* d_in, const int* in_sizes, int n_in,
                              void* d_out, int out_size, void* d_ws, size_t ws_size,
                              hipStream_t stream) {
    const float* input_state = (const float*)d_in[0];  // [4096][2048]
    const float* angles      = (const float*)d_in[1];  // [16][2048][3]
    const float* W           = (const float*)d_in[2];  // [16][2048][2048]
    const float* Mb          = (const float*)d_in[3];  // [2048][2048]

    const size_t mat = (size_t)QD * QD;
    char* ws = (char*)d_ws;
    float* scales = (float*)ws;
    size_t off = 131072;
    unsigned short* xb = (unsigned short*)(ws + off); off += (size_t)BATCH * QD * 2;
    unsigned short* WA = (unsigned short*)(ws + off); off += 8 * mat * 2;
    unsigned short* WB = (unsigned short*)(ws + off); off += 9 * mat * 2;
    unsigned short* T1 = (unsigned short*)(ws + off); off += 8 * mat * 2;
    unsigned short* T2 = (unsigned short*)(ws + off); off += 4 * mat * 2;
    unsigned short* T3 = (unsigned short*)(ws + off); off += 2 * mat * 2;
    unsigned short* T4 = (unsigned short*)(ws + off); off += mat * 2;
    unsigned short* T5 = (unsigned short*)(ws + off); off += mat * 2;

    scales_kernel<<<(L_LAYERS * QD + 255) / 256, 256, 0, stream>>>(angles, scales,
                                                                   L_LAYERS * QD);
    convert_in_kernel<<<(BATCH * QD / 4) / 256, 256, 0, stream>>>(input_state, xb,
                                                                  BATCH * QD / 4);
    convert_a_all<<<dim3(mat / 4 / 256, 1, 8), 256, 0, stream>>>(W, scales, WA);
    convert_b_all<<<dim3(QD / 64, QD / 64, 9), 256, 0, stream>>>(W, Mb, scales, WB);

    // Level 1: pair i covers layers (2i, 2i+1); odd pairs produce P^T via swap.
    GemmBatch b1{};
    for (int i = 0; i < 8; i++) {
        const unsigned short* wa = WA + (size_t)i * mat;
        const unsigned short* wb = WB + (size_t)i * mat;
        if ((i & 1) == 0) { b1.a[i] = wa; b1.b[i] = wb; }
        else              { b1.a[i] = wb; b1.b[i] = wa; }
        b1.c[i] = T1 + (size_t)i * mat;
    }
    gemm256_kernel<1><<<dim3(QD / 256, QD / 256, 8), 512, 0, stream>>>(b1);

    // Level 2
    GemmBatch b2{};
    for (int i = 0; i < 4; i++) {
        b2.a[i] = T1 + (size_t)(2 * i + (i & 1)) * mat;
        b2.b[i] = T1 + (size_t)(2 * i + 1 - (i & 1)) * mat;
        b2.c[i] = T2 + (size_t)i * mat;
    }
    gemm256_kernel<1><<<dim3(QD / 256, QD / 256, 4), 512, 0, stream>>>(b2);

    // Level 3 (128-tile kernel keeps full-GPU block count)
    GemmBatch b3{};
    for (int i = 0; i < 2; i++) {
        b3.a[i] = T2 + (size_t)(2 * i + (i & 1)) * mat;
        b3.b[i] = T2 + (size_t)(2 * i + 1 - (i & 1)) * mat;
        b3.c[i] = T3 + (size_t)i * mat;
    }
    gemm_kernel<1, 128><<<dim3(QD / 128, QD / 128, 2), 256, 0, stream>>>(b3);

    // Level 4
    GemmBatch b4{};
    b4.a[0] = T3; b4.b[0] = T3 + mat; b4.c[0] = T4;
    gemm_kernel<1, 64><<<dim3(QD / 128, QD / 64, 1), 256, 0, stream>>>(b4);

    // Level 5: T^T = M^T * S^T
    GemmBatch b5{};
    b5.a[0] = WB + 8 * mat; b5.b[0] = T4; b5.c[0] = T5;
    gemm_kernel<1, 64><<<dim3(QD / 128, QD / 64, 1), 256, 0, stream>>>(b5);

    // Apply: out = x * T, fp32 out
    GemmBatch ba{};
    ba.a[0] = xb; ba.b[0] = T5; ba.c[0] = d_out;
    gemm_kernel<0, 128><<<dim3(QD / 128, BATCH / 128, 1), 256, 0, stream>>>(ba);
}

// Round 3
// 733.281 us; speedup vs baseline: 1.0707x; 1.0155x over previous
//
#include <hip/hip_runtime.h>
#include <stdint.h>

#define L_LAYERS 16
#define QD 2048
#define BATCH 4096

typedef __attribute__((ext_vector_type(8))) __bf16 bf16x8;
typedef __attribute__((ext_vector_type(4))) float f32x4;
typedef __attribute__((address_space(3))) uint32_t lds32_t;
typedef const __attribute__((address_space(1))) uint32_t glob32_t;

// async global->LDS, 16B per lane. LDS dest is wave-uniform base + lane*16.
__device__ __forceinline__ void async_load16(const void* g, void* l) {
    __builtin_amdgcn_global_load_lds((glob32_t*)(uintptr_t)g, (lds32_t*)(uintptr_t)l,
                                     16, 0, 0);
}

// float -> bf16 bits, round-to-nearest-even.
__device__ __forceinline__ unsigned short f2bf(float f) {
    uint32_t u = __float_as_uint(f);
    u += 0x7FFFu + ((u >> 16) & 1u);
    return (unsigned short)(u >> 16);
}

// layer scale s[k] = cos(a0/2)*cos(a1/2)*cos(a2/2), fused into converters
// (HBM-bound kernels -> the 3 cosf are free under memory).
__device__ __forceinline__ float layer_scale(const float* __restrict__ ang,
                                             int lay, int k) {
    const float* ap = ang + ((size_t)lay * QD + k) * 3;
    return __cosf(ap[0] * 0.5f) * __cosf(ap[1] * 0.5f) * __cosf(ap[2] * 0.5f);
}

// ---------------------------------------------------------------------------
// fp32 input state -> bf16
__global__ void convert_in_kernel(const float* __restrict__ in,
                                  unsigned short* __restrict__ out, int n4) {
    int i = blockIdx.x * 256 + threadIdx.x;
    if (i < n4) {
        float4 v = ((const float4*)in)[i];
        ushort4 o;
        o.x = f2bf(v.x); o.y = f2bf(v.y); o.z = f2bf(v.z); o.w = f2bf(v.w);
        ((ushort4*)out)[i] = o;
    }
}

// A-form: dst[m][k] = bf16( W[2z][m][k] * s[2z][m] )  (row scale, no transpose)
__global__ void convert_a_all(const float* __restrict__ W, const float* __restrict__ ang,
                              unsigned short* __restrict__ out) {
    const int z = blockIdx.z;
    const float* src = W + (size_t)(2 * z) * QD * QD;
    unsigned short* dst = out + (size_t)z * QD * QD;
    int i = blockIdx.x * 256 + threadIdx.x;      // float4 index; 512 per row
    float s = layer_scale(ang, 2 * z, i >> 9);
    float4 v = ((const float4*)src)[i];
    ushort4 o;
    o.x = f2bf(v.x * s); o.y = f2bf(v.y * s); o.z = f2bf(v.z * s); o.w = f2bf(v.w * s);
    ((ushort4*)dst)[i] = o;
}

// 64x64 tile: dst[n][k] = bf16( src[k][n] * scale[k] )   (transpose + scale-fold)
// LDS tile uses a col-granule XOR swizzle: physical col = col ^ (((row>>2)&7)<<3).
// Old [64][72] pad gave ~16-way write conflicts (byte stride 144*(t&15) between
// lanes collapses to 2-4 banks); the XOR spreads writes to >=8 banks and keeps
// the 16B-aligned float4 read phase conflict-free.
__device__ __forceinline__ void conv_tile_body(const float* __restrict__ src,
                                               const float* __restrict__ ang,
                                               int lay,   // -1 => no scale
                                               unsigned short* __restrict__ dst) {
    __shared__ __align__(16) unsigned short tile[64][64];
    const int t = threadIdx.x;
    const int k0 = blockIdx.y * 64, n0 = blockIdx.x * 64;
    const int r = t >> 4;               // 0..15 (k within granule of 16)
    const int c = (t & 15) * 4;         // n-row base; rows c..c+3 share row>>2 = t&15
    const int g = (t & 7) << 3;         // ((row>>2)&7)<<3 for this thread's rows
#pragma unroll
    for (int rr = 0; rr < 64; rr += 16) {
        int k = k0 + r + rr;
        float s = (lay >= 0) ? layer_scale(ang, lay, k) : 1.0f;
        float4 v = *(const float4*)(src + (size_t)k * QD + n0 + c);
        int col = (r + rr) ^ g;         // swizzled physical column
        tile[c + 0][col] = f2bf(v.x * s);
        tile[c + 1][col] = f2bf(v.y * s);
        tile[c + 2][col] = f2bf(v.z * s);
        tile[c + 3][col] = f2bf(v.w * s);
    }
    __syncthreads();
    const int wr = t >> 3;              // 0..31
    const int wc = (t & 7) * 8;         // granule-aligned logical col
#pragma unroll
    for (int rr = 0; rr < 64; rr += 32) {
        int row = wr + rr;
        int pc = wc ^ (((row >> 2) & 7) << 3);
        *(float4*)(dst + (size_t)(n0 + row) * QD + k0 + wc) =
            *(const float4*)(&tile[row][pc]);
    }
}

__global__ void convert_b_all(const float* __restrict__ W, const float* __restrict__ Mb,
                              const float* __restrict__ ang, unsigned short* __restrict__ out) {
    const int z = blockIdx.z;
    const float* src = (z < 8) ? (W + (size_t)(2 * z + 1) * QD * QD) : Mb;
    const int lay = (z < 8) ? (2 * z + 1) : -1;
    unsigned short* dst = out + (size_t)z * QD * QD;
    conv_tile_body(src, ang, lay, dst);
}

// ---------------------------------------------------------------------------
struct GemmBatch {
    const unsigned short* a[8];
    const unsigned short* b[8];
    void* c[8];
};

// ======================= 128-wide kernel (small levels) =====================
// Kept unswizzled: T2 is measured-null on 2-phase structures (regime gate);
// T1 likewise omitted (working sets L3-resident -> measured ~-2%).
template <int OUT_BF16, int TM>
__global__ __launch_bounds__(256, TM == 128 ? 2 : 4)
void gemm_kernel(GemmBatch args) {
    constexpr int NI = TM / 32;
    __shared__ __align__(16) unsigned short ldsA[TM * 64];
    __shared__ __align__(16) unsigned short ldsB[128 * 64];
    const unsigned short* __restrict__ A  = args.a[blockIdx.z];
    const unsigned short* __restrict__ Bt = args.b[blockIdx.z];
    void* __restrict__ Cout = args.c[blockIdx.z];

    const int t = threadIdx.x;
    const int n0 = blockIdx.x * 128;
    const int m0 = blockIdx.y * TM;
    const int lane = t & 63;
    const int wave = t >> 6;
    const int wm = (wave & 1) * (TM / 2);
    const int wn = (wave >> 1) * 64;
    const int fr = lane & 15;
    const int quad = lane >> 4;

    f32x4 acc[NI][4] = {};

    const int sr = t >> 2;
    const int scol = (t & 3) * 8;
    const unsigned short* ga = A + (size_t)(m0 + sr) * QD + scol;
    const unsigned short* gb = Bt + (size_t)(n0 + sr) * QD + scol;
    unsigned short* la = ldsA + t * 8;
    unsigned short* lb = ldsB + t * 8;

    for (int k0 = 0; k0 < QD; k0 += 64) {
        __syncthreads();
        if constexpr (TM == 128) {
            async_load16(ga, la);
            async_load16(ga + 64 * QD, la + 2048);
            async_load16(ga + 32, la + 4096);
            async_load16(ga + 32 + 64 * QD, la + 6144);
        } else {
            async_load16(ga, la);
            async_load16(ga + 32, la + 2048);
        }
        async_load16(gb, lb);
        async_load16(gb + 64 * QD, lb + 2048);
        async_load16(gb + 32, lb + 4096);
        async_load16(gb + 32 + 64 * QD, lb + 6144);
        ga += 64;
        gb += 64;
        __syncthreads();

#pragma unroll
        for (int kk = 0; kk < 2; kk++) {
            const unsigned short* pa = ldsA + kk * (TM * 32);
            const unsigned short* pb = ldsB + kk * 4096;
            bf16x8 af[NI], bfr[4];
#pragma unroll
            for (int i = 0; i < NI; i++)
                af[i] = *(const bf16x8*)(pa + (wm + i * 16 + fr) * 32 + quad * 8);
#pragma unroll
            for (int j = 0; j < 4; j++)
                bfr[j] = *(const bf16x8*)(pb + (wn + j * 16 + fr) * 32 + quad * 8);
#pragma unroll
            for (int i = 0; i < NI; i++)
#pragma unroll
                for (int j = 0; j < 4; j++)
                    acc[i][j] = __builtin_amdgcn_mfma_f32_16x16x32_bf16(af[i], bfr[j],
                                                                        acc[i][j], 0, 0, 0);
        }
    }

#pragma unroll
    for (int i = 0; i < NI; i++) {
        const int gr = m0 + wm + i * 16 + quad * 4;
#pragma unroll
        for (int j = 0; j < 4; j++) {
            const int gc = n0 + wn + j * 16 + fr;
#pragma unroll
            for (int r = 0; r < 4; r++) {
                float v = acc[i][j][r];
                if (OUT_BF16)
                    ((unsigned short*)Cout)[(size_t)(gr + r) * QD + gc] = f2bf(v);
                else
                    ((float*)Cout)[(size_t)(gr + r) * QD + gc] = v;
            }
        }
    }
}

// ================== 256x256 8-phase kernel (batched levels) =================
// BM=BN=256, BK=64, 512 threads = 8 waves (2m x 4n), per-wave 128x64 output.
// LDS 128 KiB: A/B each 2 dbuf x 2 halves x [128 rows][64 cols] bf16.
// Bank-conflict fix (Guideline 4, 3-bit XOR for 128B rows):
//   lds_byte(row, col_byte) holds global col_byte ^ ((row&7)<<4).
// Applied as inverse-swizzled global_load_lds SOURCE (linear dest, rule #21)
// + swizzled ds_read addresses (folded to per-thread constants).
// XCD swizzle (T1): grid is always (8, 8, gz) with nwg % 8 == 0; remap so each
// XCD gets a contiguous 64*gz/8-block chunk -> one z-matrix-pair per XCD at
// gz=8 (per-XCD L2 working set 128MB -> 16MB; R0 measured 2.5x HBM overfetch
// from the default scattered mapping).
// Staging schedule (race-free; each slot staged only after the barrier
// following its last read): tile t phases: p1 A1(t+1)->nbuf, p2 B1(t+1)->nbuf,
// p3 B0(t+2)->buf, p4 A0(t+2)->buf; one counted vmcnt(4) per K-tile (p4).
// Tail tiles stage clamped-k dummy data into slots never read again.
__device__ __forceinline__ void stage_half(const unsigned short* __restrict__ G,
                                           int row0, int k0,
                                           unsigned char* dst, int t) {
    const int r = t >> 3;
    const int c = 8 * ((t & 7) ^ (r & 7));   // inverse-swizzled source col (elements)
    const unsigned short* g = G + (size_t)(row0 + r) * QD + k0 + c;
    async_load16(g, dst + t * 16);
    async_load16(g + 64 * QD, dst + 8192 + t * 16);   // rows 64..127: (r+64)&7 == r&7
}

template <int OUT_BF16>
__global__ __launch_bounds__(512, 2)
void gemm256_kernel(GemmBatch args) {
    __shared__ __align__(16) unsigned char lds[131072];

    // T1 XCD-aware block swizzle (grid fixed at 8 x 8 x gz, nwg % 8 == 0)
    const int lin = blockIdx.x + ((blockIdx.y + (blockIdx.z << 3)) << 3);
    const int cpx = gridDim.z << 3;              // nwg/8
    const int m = (lin & 7) * cpx + (lin >> 3);
    const int bx = m & 7, by = (m >> 3) & 7, bz = m >> 6;

    const unsigned short* __restrict__ A  = args.a[bz];
    const unsigned short* __restrict__ Bt = args.b[bz];
    void* __restrict__ Cout = args.c[bz];

    const int t = threadIdx.x;
    const int lane = t & 63;
    const int wid = t >> 6;
    const int wm = (wid >> 2) * 128;       // 0 or 128
    const int wn = (wid & 3) * 64;         // 0,64,128,192
    const int fr = lane & 15;
    const int quad = lane >> 4;
    const int m0 = by * 256;
    const int n0 = bx * 256;

    unsigned char* ldsA8 = lds;            // 64 KiB
    unsigned char* ldsB8 = lds + 65536;    // 64 KiB
    // 3-bit swizzle folded per-thread: bits 4-5 from fr bits 0-1, bit 6 swaps kk.
    const int swz45 = (fr & 3) << 4;
    const int frb2 = (fr >> 2) & 1;
    const int kof0 = frb2 << 6;            // byte offset of k-slice kk=0
    const int kof1 = (frb2 ^ 1) << 6;      // byte offset of k-slice kk=1
    const unsigned char* sA = ldsA8 + (wm >> 7) * 16384 + fr * 128 + ((quad * 16) ^ swz45);
    const unsigned char* sB = ldsB8 + ((wn >> 7) & 1) * 16384 + (wn & 64) * 128
                              + fr * 128 + ((quad * 16) ^ swz45);

    f32x4 acc[8][4] = {};
    bf16x8 af[4][2], bfA[2][2], bfB[2][2];

    constexpr int NT = QD / 64;            // 32 K-tiles

    // prologue: all of tile 0 + A0(1), B0(1); leave 2 halves (4 loads) in flight
    stage_half(A,  m0,       0,  ldsA8,         t);   // A0(0)
    stage_half(A,  m0 + 128, 0,  ldsA8 + 16384, t);   // A1(0)
    stage_half(Bt, n0,       0,  ldsB8,         t);   // B0(0)
    stage_half(Bt, n0 + 128, 0,  ldsB8 + 16384, t);   // B1(0)
    stage_half(A,  m0,       64, ldsA8 + 32768, t);   // A0(1)
    stage_half(Bt, n0,       64, ldsB8 + 32768, t);   // B0(1)
    asm volatile("s_waitcnt vmcnt(4)" ::: "memory");
    __builtin_amdgcn_s_barrier();

    for (int kt = 0; kt < NT; ++kt) {
        const int buf  = (kt & 1) << 15;
        const int nbuf = (~kt & 1) << 15;
        const int k1 = ((kt + 1) & (NT - 1)) << 6;   // clamped: tail stages are dummies
        const int k2 = ((kt + 2) & (NT - 1)) << 6;

        // ---- phase 1: read A(mf0-3)+B(nf0-1); stage A1(t+1); MFMA Q(0,0)
#pragma unroll
        for (int mf = 0; mf < 4; mf++)
#pragma unroll
            for (int kk = 0; kk < 2; kk++)
                af[mf][kk] = *(const bf16x8*)(sA + buf + mf * 2048 + (kk ? kof1 : kof0));
#pragma unroll
        for (int nf = 0; nf < 2; nf++)
#pragma unroll
            for (int kk = 0; kk < 2; kk++)
                bfA[nf][kk] = *(const bf16x8*)(sB + buf + nf * 2048 + (kk ? kof1 : kof0));
        stage_half(A, m0 + 128, k1, ldsA8 + nbuf + 16384, t);
        __builtin_amdgcn_s_barrier();
        __builtin_amdgcn_s_setprio(1);
#pragma unroll
        for (int mf = 0; mf < 4; mf++)
#pragma unroll
            for (int nf = 0; nf < 2; nf++)
#pragma unroll
                for (int kk = 0; kk < 2; kk++)
                    acc[mf][nf] = __builtin_amdgcn_mfma_f32_16x16x32_bf16(
                        af[mf][kk], bfA[nf][kk], acc[mf][nf], 0, 0, 0);
        __builtin_amdgcn_s_setprio(0);
        __builtin_amdgcn_s_barrier();

        // ---- phase 2: read B(nf2-3); stage B1(t+1); MFMA Q(0,1)
#pragma unroll
        for (int nf = 0; nf < 2; nf++)
#pragma unroll
            for (int kk = 0; kk < 2; kk++)
                bfB[nf][kk] = *(const bf16x8*)(sB + buf + (nf + 2) * 2048 + (kk ? kof1 : kof0));
        stage_half(Bt, n0 + 128, k1, ldsB8 + nbuf + 16384, t);
        __builtin_amdgcn_s_barrier();
        __builtin_amdgcn_s_setprio(1);
#pragma unroll
        for (int mf = 0; mf < 4; mf++)
#pragma unroll
            for (int nf = 0; nf < 2; nf++)
#pragma unroll
                for (int kk = 0; kk < 2; kk++)
                    acc[mf][nf + 2] = __builtin_amdgcn_mfma_f32_16x16x32_bf16(
                        af[mf][kk], bfB[nf][kk], acc[mf][nf + 2], 0, 0, 0);
        __builtin_amdgcn_s_setprio(0);
        __builtin_amdgcn_s_barrier();

        // ---- phase 3: read A(mf4-7); stage B0(t+2); MFMA Q(1,1)
#pragma unroll
        for (int mf = 0; mf < 4; mf++)
#pragma unroll
            for (int kk = 0; kk < 2; kk++)
                af[mf][kk] = *(const bf16x8*)(sA + buf + (mf + 4) * 2048 + (kk ? kof1 : kof0));
        stage_half(Bt, n0, k2, ldsB8 + buf, t);
        __builtin_amdgcn_s_barrier();
        __builtin_amdgcn_s_setprio(1);
#pragma unroll
        for (int mf = 0; mf < 4; mf++)
#pragma unroll
            for (int nf = 0; nf < 2; nf++)
#pragma unroll
                for (int kk = 0; kk < 2; kk++)
                    acc[mf + 4][nf + 2] = __builtin_amdgcn_mfma_f32_16x16x32_bf16(
                        af[mf][kk], bfB[nf][kk], acc[mf + 4][nf + 2], 0, 0, 0);
        __builtin_amdgcn_s_setprio(0);
        __builtin_amdgcn_s_barrier();

        // ---- phase 4: no ds reads (reuse af + held bfA); stage A0(t+2);
        //      MFMA Q(1,0); counted vmcnt -> next tile fully staged
        stage_half(A, m0, k2, ldsA8 + buf, t);
        __builtin_amdgcn_s_barrier();
        __builtin_amdgcn_s_setprio(1);
#pragma unroll
        for (int mf = 0; mf < 4; mf++)
#pragma unroll
            for (int nf = 0; nf < 2; nf++)
#pragma unroll
                for (int kk = 0; kk < 2; kk++)
                    acc[mf + 4][nf] = __builtin_amdgcn_mfma_f32_16x16x32_bf16(
                        af[mf][kk], bfA[nf][kk], acc[mf + 4][nf], 0, 0, 0);
        __builtin_amdgcn_s_setprio(0);
        asm volatile("s_waitcnt vmcnt(4)" ::: "memory");
        __builtin_amdgcn_s_barrier();
    }

    asm volatile("s_waitcnt vmcnt(0)" ::: "memory");  // drain dummy tail stages

    // epilogue: C/D layout col=lane&15, row=quad*4+reg (m89/m91-verified)
#pragma unroll
    for (int mf = 0; mf < 8; mf++) {
        const int gr = m0 + wm + mf * 16 + quad * 4;
#pragma unroll
        for (int nf = 0; nf < 4; nf++) {
            const int gc = n0 + wn + nf * 16 + fr;
#pragma unroll
            for (int r = 0; r < 4; r++) {
                float v = acc[mf][nf][r];
                if (OUT_BF16)
                    ((unsigned short*)Cout)[(size_t)(gr + r) * QD + gc] = f2bf(v);
                else
                    ((float*)Cout)[(size_t)(gr + r) * QD + gc] = v;
            }
        }
    }
}

// ---------------------------------------------------------------------------
extern "C" void kernel_launch(void* const* d_in, const int* in_sizes, int n_in,
                              void* d_out, int out_size, void* d_ws, size_t ws_size,
                              hipStream_t stream) {
    const float* input_state = (const float*)d_in[0];  // [4096][2048]
    const float* angles      = (const float*)d_in[1];  // [16][2048][3]
    const float* W           = (const float*)d_in[2];  // [16][2048][2048]
    const float* Mb          = (const float*)d_in[3];  // [2048][2048]

    const size_t mat = (size_t)QD * QD;
    char* ws = (char*)d_ws;
    size_t off = 131072;                               // (region kept reserved)
    unsigned short* xb = (unsigned short*)(ws + off); off += (size_t)BATCH * QD * 2;
    unsigned short* WA = (unsigned short*)(ws + off); off += 8 * mat * 2;
    unsigned short* WB = (unsigned short*)(ws + off); off += 9 * mat * 2;
    unsigned short* T1 = (unsigned short*)(ws + off); off += 8 * mat * 2;
    unsigned short* T2 = (unsigned short*)(ws + off); off += 4 * mat * 2;
    unsigned short* T3 = (unsigned short*)(ws + off); off += 2 * mat * 2;
    unsigned short* T4 = (unsigned short*)(ws + off); off += mat * 2;
    unsigned short* T5 = (unsigned short*)(ws + off); off += mat * 2;

    convert_in_kernel<<<(BATCH * QD / 4) / 256, 256, 0, stream>>>(input_state, xb,
                                                                  BATCH * QD / 4);
    convert_a_all<<<dim3(mat / 4 / 256, 1, 8), 256, 0, stream>>>(W, angles, WA);
    convert_b_all<<<dim3(QD / 64, QD / 64, 9), 256, 0, stream>>>(W, Mb, angles, WB);

    // Level 1: pair i covers layers (2i, 2i+1); odd pairs produce P^T via swap.
    GemmBatch b1{};
    for (int i = 0; i < 8; i++) {
        const unsigned short* wa = WA + (size_t)i * mat;
        const unsigned short* wb = WB + (size_t)i * mat;
        if ((i & 1) == 0) { b1.a[i] = wa; b1.b[i] = wb; }
        else              { b1.a[i] = wb; b1.b[i] = wa; }
        b1.c[i] = T1 + (size_t)i * mat;
    }
    gemm256_kernel<1><<<dim3(QD / 256, QD / 256, 8), 512, 0, stream>>>(b1);

    // Level 2
    GemmBatch b2{};
    for (int i = 0; i < 4; i++) {
        b2.a[i] = T1 + (size_t)(2 * i + (i & 1)) * mat;
        b2.b[i] = T1 + (size_t)(2 * i + 1 - (i & 1)) * mat;
        b2.c[i] = T2 + (size_t)i * mat;
    }
    gemm256_kernel<1><<<dim3(QD / 256, QD / 256, 4), 512, 0, stream>>>(b2);

    // Level 3 (128-tile kernel keeps full-GPU block count)
    GemmBatch b3{};
    for (int i = 0; i < 2; i++) {
        b3.a[i] = T2 + (size_t)(2 * i + (i & 1)) * mat;
        b3.b[i] = T2 + (size_t)(2 * i + 1 - (i & 1)) * mat;
        b3.c[i] = T3 + (size_t)i * mat;
    }
    gemm_kernel<1, 128><<<dim3(QD / 128, QD / 128, 2), 256, 0, stream>>>(b3);

    // Level 4
    GemmBatch b4{};
    b4.a[0] = T3; b4.b[0] = T3 + mat; b4.c[0] = T4;
    gemm_kernel<1, 64><<<dim3(QD / 128, QD / 64, 1), 256, 0, stream>>>(b4);

    // Level 5: T^T = M^T * S^T
    GemmBatch b5{};
    b5.a[0] = WB + 8 * mat; b5.b[0] = T4; b5.c[0] = T5;
    gemm_kernel<1, 64><<<dim3(QD / 128, QD / 64, 1), 256, 0, stream>>>(b5);

    // Apply: out = x * T, fp32 out
    GemmBatch ba{};
    ba.a[0] = xb; ba.b[0] = T5; ba.c[0] = d_out;
    gemm_kernel<0, 128><<<dim3(QD / 128, BATCH / 128, 1), 256, 0, stream>>>(ba);
}